// Round 1
// baseline (685.441 us; speedup 1.0000x reference)
//
#include <hip/hip_runtime.h>

// SafenessLoss: K=8 streams, B samples, D=128.
// One half-wave (32 lanes) per sample; lane h loads float4 of each stream row.
// Memory-bound: 512 MiB embeddings read once -> roofline ~86 us @ 6.3 TB/s.

#define DDIM 128
#define NBLOCKS 1024

__global__ __launch_bounds__(256) void safeness_main(
    const float* __restrict__ emb, const int* __restrict__ target,
    int B, float* __restrict__ ws) {
  const int tid = threadIdx.x;
  const int h = tid & 31;              // lane within 32-lane half-wave
  const int sp = blockIdx.x * 8 + (tid >> 5);   // sample-processor id
  const int P = gridDim.x * 8;
  const long long strideK = (long long)B * DDIM;

  float part_loss = 0.f, part_cnt = 0.f;

  for (int b = sp; b < B; b += P) {
    const float* base = emb + (long long)b * DDIM + h * 4;
    float4 a = *(const float4*)(base);
    float4 e[7];
#pragma unroll
    for (int k = 0; k < 7; ++k)
      e[k] = *(const float4*)(base + (long long)(k + 1) * strideK);

    int t0 = target[b];
    int tk[7];
#pragma unroll
    for (int k = 0; k < 7; ++k) tk[k] = target[(k + 1) * B + b];

    float dist[7];
#pragma unroll
    for (int k = 0; k < 7; ++k) {
      float dx = a.x - e[k].x;
      float dy = a.y - e[k].y;
      float dz = a.z - e[k].z;
      float dw = a.w - e[k].w;
      float s = dx * dx + dy * dy + dz * dz + dw * dw;
      // butterfly sum within the 32-lane half (masks 1..16 never cross halves)
      s += __shfl_xor(s, 1);
      s += __shfl_xor(s, 2);
      s += __shfl_xor(s, 4);
      s += __shfl_xor(s, 8);
      s += __shfl_xor(s, 16);
      dist[k] = s;   // broadcast to all 32 lanes of the half
    }

    bool any_same = false;
    bool same[7];
    float same_sum = 0.f, mmax = -INFINITY;
#pragma unroll
    for (int k = 0; k < 7; ++k) {
      same[k] = (tk[k] == t0);
      if (same[k]) {
        any_same = true;
        same_sum += dist[k];
        mmax = fmaxf(mmax, dist[k]);
      }
    }
    float alpha = any_same ? mmax : 1.0f;

    float neg_sum = 0.f;
    bool any_neg = false;
#pragma unroll
    for (int k = 0; k < 7; ++k) {
      float m = dist[k] - alpha;
      if (!same[k] && m < 0.f) {
        neg_sum += m;
        any_neg = true;
      }
    }
    bool include = any_same || any_neg;
    if (h == 0 && include) {
      part_loss += same_sum - neg_sum;
      part_cnt += 1.f;
    }
  }

  // full-wave butterfly (non-h0 lanes hold 0)
#pragma unroll
  for (int m = 1; m <= 32; m <<= 1) {
    part_loss += __shfl_xor(part_loss, m);
    part_cnt += __shfl_xor(part_cnt, m);
  }

  __shared__ float s_loss[4], s_cnt[4];
  const int wave = tid >> 6;
  if ((tid & 63) == 0) { s_loss[wave] = part_loss; s_cnt[wave] = part_cnt; }
  __syncthreads();
  if (tid == 0) {
    float L = s_loss[0] + s_loss[1] + s_loss[2] + s_loss[3];
    float C = s_cnt[0] + s_cnt[1] + s_cnt[2] + s_cnt[3];
    atomicAdd(&ws[0], L);
    atomicAdd(&ws[1], C);
  }
}

__global__ void safeness_final(const float* __restrict__ ws,
                               float* __restrict__ out) {
  out[0] = ws[0] / fmaxf(ws[1], 1.0f);
}

extern "C" void kernel_launch(void* const* d_in, const int* in_sizes, int n_in,
                              void* d_out, int out_size, void* d_ws, size_t ws_size,
                              hipStream_t stream) {
  const float* emb = (const float*)d_in[0];
  const int* target = (const int*)d_in[1];
  const int B = in_sizes[1] / 8;   // target is [K=8, B]
  float* ws = (float*)d_ws;

  hipMemsetAsync(d_ws, 0, 2 * sizeof(float), stream);
  safeness_main<<<NBLOCKS, 256, 0, stream>>>(emb, target, B, ws);
  safeness_final<<<1, 1, 0, stream>>>(ws, (float*)d_out);
}

// Round 2
// 685.013 us; speedup vs baseline: 1.0006x; 1.0006x over previous
//
#include <hip/hip_runtime.h>

// SafenessLoss: K=8 streams, B=131072 samples, D=128, fp32.
// Memory-bound: 512 MiB embeddings read exactly once -> ~86 us @ 6.3 TB/s.
// One half-wave (32 lanes) per sample: lane h loads float4 (16 B) of each
// stream row -> fully coalesced 512 B/stream/half-wave.
// No atomics: per-block partials to private ws slots, tiny final reduce.

#define NBLOCKS 2048

__global__ __launch_bounds__(256) void safeness_main(
    const float* __restrict__ emb, const int* __restrict__ target,
    int B, float* __restrict__ ws) {
  const int tid = threadIdx.x;
  const int h = tid & 31;                        // lane within half-wave
  const int sp = blockIdx.x * 8 + (tid >> 5);    // sample-processor id
  const int P = NBLOCKS * 8;                     // 16384 processors
  const long long strideK = (long long)B * 128;

  float part_loss = 0.f, part_cnt = 0.f;

  for (int b = sp; b < B; b += P) {
    const float* base = emb + (long long)b * 128 + h * 4;
    float4 a = *(const float4*)(base);
    float4 e[7];
#pragma unroll
    for (int k = 0; k < 7; ++k)
      e[k] = *(const float4*)(base + (long long)(k + 1) * strideK);

    int t0 = target[b];
    int tk[7];
#pragma unroll
    for (int k = 0; k < 7; ++k) tk[k] = target[(k + 1) * B + b];

    float dist[7];
#pragma unroll
    for (int k = 0; k < 7; ++k) {
      float dx = a.x - e[k].x;
      float dy = a.y - e[k].y;
      float dz = a.z - e[k].z;
      float dw = a.w - e[k].w;
      float s = dx * dx + dy * dy + dz * dz + dw * dw;
      // butterfly within the 32-lane half (masks 1..16 stay in-half)
      s += __shfl_xor(s, 1);
      s += __shfl_xor(s, 2);
      s += __shfl_xor(s, 4);
      s += __shfl_xor(s, 8);
      s += __shfl_xor(s, 16);
      dist[k] = s;                               // broadcast across the half
    }

    bool any_same = false;
    bool same[7];
    float same_sum = 0.f, mmax = -INFINITY;
#pragma unroll
    for (int k = 0; k < 7; ++k) {
      same[k] = (tk[k] == t0);
      if (same[k]) {
        any_same = true;
        same_sum += dist[k];
        mmax = fmaxf(mmax, dist[k]);
      }
    }
    float alpha = any_same ? mmax : 1.0f;

    float neg_sum = 0.f;
    bool any_neg = false;
#pragma unroll
    for (int k = 0; k < 7; ++k) {
      float m = dist[k] - alpha;
      if (!same[k] && m < 0.f) {
        neg_sum += m;
        any_neg = true;
      }
    }
    if (h == 0 && (any_same || any_neg)) {
      part_loss += same_sum - neg_sum;
      part_cnt += 1.f;
    }
  }

  // full-wave butterfly (only lanes 0 and 32 hold nonzero)
#pragma unroll
  for (int m = 1; m <= 32; m <<= 1) {
    part_loss += __shfl_xor(part_loss, m);
    part_cnt += __shfl_xor(part_cnt, m);
  }

  __shared__ float s_loss[4], s_cnt[4];
  const int wave = tid >> 6;
  if ((tid & 63) == 0) { s_loss[wave] = part_loss; s_cnt[wave] = part_cnt; }
  __syncthreads();
  if (tid == 0) {
    // private slot per block -- no atomics, no memset needed
    ws[2 * blockIdx.x]     = s_loss[0] + s_loss[1] + s_loss[2] + s_loss[3];
    ws[2 * blockIdx.x + 1] = s_cnt[0] + s_cnt[1] + s_cnt[2] + s_cnt[3];
  }
}

__global__ __launch_bounds__(256) void safeness_final(
    const float* __restrict__ ws, float* __restrict__ out) {
  const int tid = threadIdx.x;
  float L = 0.f, C = 0.f;
  for (int i = tid; i < NBLOCKS; i += 256) {
    L += ws[2 * i];
    C += ws[2 * i + 1];
  }
#pragma unroll
  for (int m = 1; m <= 32; m <<= 1) {
    L += __shfl_xor(L, m);
    C += __shfl_xor(C, m);
  }
  __shared__ float s_loss[4], s_cnt[4];
  const int wave = tid >> 6;
  if ((tid & 63) == 0) { s_loss[wave] = L; s_cnt[wave] = C; }
  __syncthreads();
  if (tid == 0) {
    float Lt = s_loss[0] + s_loss[1] + s_loss[2] + s_loss[3];
    float Ct = s_cnt[0] + s_cnt[1] + s_cnt[2] + s_cnt[3];
    out[0] = Lt / fmaxf(Ct, 1.0f);
  }
}

extern "C" void kernel_launch(void* const* d_in, const int* in_sizes, int n_in,
                              void* d_out, int out_size, void* d_ws, size_t ws_size,
                              hipStream_t stream) {
  const float* emb = (const float*)d_in[0];
  const int* target = (const int*)d_in[1];
  const int B = in_sizes[1] / 8;   // target is [K=8, B]
  float* ws = (float*)d_ws;

  safeness_main<<<NBLOCKS, 256, 0, stream>>>(emb, target, B, ws);
  safeness_final<<<1, 256, 0, stream>>>(ws, (float*)d_out);
}